// Round 7
// baseline (41.979 us; speedup 1.0000x reference)
//
#include <hip/hip_runtime.h>
#include <cstdint>

// MultiboxLoss: B=128, P=8732, C=21
//   out[0] = smooth_ex_loss_sum(pos) / n_pos_total
//   out[1] = CE_sum(pos | mined_neg) / n_pos_total
// Hot path: 3*num_pos >= #negatives -> mined set = ALL priors (decided per row
// at runtime; general top-k fallback kept in k_tail cold path).
// R7: wave-autonomous DMA pipeline. R2-R4: coalesced global_load_lds but
// cross-wave __syncthreads lockstep (12% VALU). R5/R6: no barriers but the
// backend scheduler serialized direct loads (VGPR 48 != predicted 100+;
// warm==cold ~52us latency-bound; 84B-stride loads also TA-hostile).
// Now: per-WAVE private LDS double buffer + global_load_lds (coalesced,
// no VGPRs needed for in-flight data) + per-wave s_waitcnt vmcnt(0) only
// (no __syncthreads in loop) -> waves stall independently, 14 waves/CU.

#define B_ 128
#define P_ 8732
#define C_ 21
constexpr int TPB = 128;               // 2 waves per block
constexpr int SPR = 28;                // spans per row (one span per wave)
constexpr int SPAN = 312;              // ceil(P/SPR); last span = 308
constexpr int NCHK = 5;                // chunks per span: 64,64,64,64,56|52
constexpr int GRID = B_ * SPR / 2;     // 1792 blocks = 7/CU exactly
constexpr int SLOTS = SPR / 2;         // 14 part slots per row
constexpr int CHB = 64 * C_ * 4;       // 5376 B per full chunk
// All chunk prior-counts (64,56,52) are multiples of 4 -> stage bytes are
// multiples of 16 -> no ragged 16B tail in global_load_lds.

typedef const __attribute__((address_space(1))) uint32_t* gas_u32p;
typedef __attribute__((address_space(3))) uint32_t* las_u32p;

__device__ __forceinline__ float waveSumF(float v) {
#pragma unroll
  for (int o = 32; o; o >>= 1) v += __shfl_down(v, o);
  return v;
}
__device__ __forceinline__ int waveSumI(int v) {
#pragma unroll
  for (int o = 32; o; o >>= 1) v += __shfl_down(v, o);
  return v;
}
__device__ __forceinline__ double waveSumD(double v) {
#pragma unroll
  for (int o = 32; o; o >>= 1) v += __shfl_down(v, o);
  return v;
}

// stage one chunk (bytes multiple of 16, <= 5376) into this wave's LDS buffer
__device__ __forceinline__ void stage(const char* g, float* l, int bytes, int lane) {
#pragma unroll
  for (int j = 0; j < 6; ++j) {
    const int off = (j << 10) + (lane << 4);
    if (off < bytes)  // bytes % 16 == 0, so off<bytes <=> off+16<=bytes
      __builtin_amdgcn_global_load_lds((gas_u32p)(g + off),
                                       (las_u32p)(l + (j << 8)), 16, 0, 0);
  }
}

#define SMEX(d) (((d) < 1.f) ? (1.1565176427496657f * ((d) + (__expf(-2.f * (d)) - 1.f) * 0.5f)) \
                             : ((d) - 0.3434823572503343f))

// one prior from LDS row lp[0..20]; contributions masked by act
__device__ __forceinline__ void prior21(const float* lp, int lab, float4 pr, float4 gv,
                                        bool act, float& sm, float& cp, float& cn, int& np) {
  const float f0 = lp[0], f1 = lp[1], f2 = lp[2], f3 = lp[3], f4 = lp[4];
  const float f5 = lp[5], f6 = lp[6], f7 = lp[7], f8 = lp[8], f9 = lp[9];
  const float f10 = lp[10], f11 = lp[11], f12 = lp[12], f13 = lp[13], f14 = lp[14];
  const float f15 = lp[15], f16 = lp[16], f17 = lp[17], f18 = lp[18], f19 = lp[19];
  const float f20 = lp[20];
  float m = fmaxf(fmaxf(fmaxf(fmaxf(f0, f1), fmaxf(f2, f3)),
                        fmaxf(fmaxf(f4, f5), fmaxf(f6, f7))),
                  fmaxf(fmaxf(fmaxf(f8, f9), fmaxf(f10, f11)),
                        fmaxf(fmaxf(f12, f13), fmaxf(f14, f15))));
  m = fmaxf(m, fmaxf(fmaxf(fmaxf(f16, f17), fmaxf(f18, f19)), f20));
  float s = __expf(f0 - m) + __expf(f1 - m) + __expf(f2 - m) + __expf(f3 - m);
  s += __expf(f4 - m) + __expf(f5 - m) + __expf(f6 - m) + __expf(f7 - m);
  s += __expf(f8 - m) + __expf(f9 - m) + __expf(f10 - m) + __expf(f11 - m);
  s += __expf(f12 - m) + __expf(f13 - m) + __expf(f14 - m) + __expf(f15 - m);
  s += __expf(f16 - m) + __expf(f17 - m) + __expf(f18 - m) + __expf(f19 - m);
  s += __expf(f20 - m);
  float xl = f0;  // f[lab] via static cndmask chain (no indexed array)
  xl = (lab == 1) ? f1 : xl;   xl = (lab == 2) ? f2 : xl;
  xl = (lab == 3) ? f3 : xl;   xl = (lab == 4) ? f4 : xl;
  xl = (lab == 5) ? f5 : xl;   xl = (lab == 6) ? f6 : xl;
  xl = (lab == 7) ? f7 : xl;   xl = (lab == 8) ? f8 : xl;
  xl = (lab == 9) ? f9 : xl;   xl = (lab == 10) ? f10 : xl;
  xl = (lab == 11) ? f11 : xl; xl = (lab == 12) ? f12 : xl;
  xl = (lab == 13) ? f13 : xl; xl = (lab == 14) ? f14 : xl;
  xl = (lab == 15) ? f15 : xl; xl = (lab == 16) ? f16 : xl;
  xl = (lab == 17) ? f17 : xl; xl = (lab == 18) ? f18 : xl;
  xl = (lab == 19) ? f19 : xl; xl = (lab == 20) ? f20 : xl;
  const float ce = m + __logf(s) - xl;

  float d, smx;
  d = fabsf(pr.x - gv.x); smx = SMEX(d);
  d = fabsf(pr.y - gv.y); smx += SMEX(d);
  d = fabsf(pr.z - gv.z); smx += SMEX(d);
  d = fabsf(pr.w - gv.w); smx += SMEX(d);

  const bool pos = act && (lab > 0);
  sm += pos ? smx : 0.f;
  cp += pos ? ce : 0.f;
  cn += (act && lab == 0) ? ce : 0.f;
  np += pos ? 1 : 0;
}

// ---------------- main kernel: wave-autonomous pipelined streaming ----------------
__global__ __launch_bounds__(TPB, 3) void k_main(
    const float* __restrict__ conf, const float* __restrict__ pred,
    const int* __restrict__ labels, const float* __restrict__ gt,
    float4* __restrict__ part) {
  __shared__ __align__(16) float sbuf[2][2][64 * C_];  // [wave][dbuf][1344] = 21504 B
  __shared__ float redf[6];
  __shared__ int redi[2];
  const int tid = threadIdx.x;
  const int wid = tid >> 6, lane = tid & 63;
  const int row = blockIdx.x / SLOTS;
  const int pair = blockIdx.x % SLOTS;
  const int s = pair * 2 + wid;            // this wave's span (same row for both waves)
  const int ps = s * SPAN;
  const int spc = min(SPAN, P_ - ps);      // 312, or 308 for the last span
  const size_t rp = (size_t)row * P_;
  const char* cbase = (const char*)conf + (rp + (size_t)ps) * (C_ * 4);
  const float4* pred4 = (const float4*)pred;
  const float4* gt4 = (const float4*)gt;
  float* wbuf0 = sbuf[wid][0];
  float* wbuf1 = sbuf[wid][1];

  // ---- prologue: stage + reg-prefetch chunk 0, drain (per-wave only) ----
  stage(cbase, wbuf0, 64 * C_ * 4, lane);
  int labr;
  float4 prr, gvr;
  {
    const size_t gp = rp + ps + lane;  // chunk0 always full (lane < 64 <= spc)
    labr = labels[gp];
    prr = pred4[gp];
    gvr = gt4[gp];
  }
  asm volatile("s_waitcnt vmcnt(0)" ::: "memory");
  __builtin_amdgcn_sched_barrier(0);

  float sm = 0.f, cp = 0.f, cn = 0.f;
  int np = 0;

#pragma unroll
  for (int k = 0; k < NCHK; ++k) {
    float* cbuf = (k & 1) ? wbuf1 : wbuf0;
    float* nbuf = (k & 1) ? wbuf0 : wbuf1;
    int labn = 0;
    float4 prn = make_float4(0, 0, 0, 0), gvn = prn;
    if (k + 1 < NCHK) {
      // issue next chunk's DMA + register prefetch (in flight during compute)
      const int cntn = min(64, spc - ((k + 1) << 6));
      stage(cbase + (size_t)(k + 1) * CHB, nbuf, cntn * (C_ * 4), lane);
      int idx = ((k + 1) << 6) + lane;
      if (idx >= spc) idx = spc - 1;  // clamp inside span (masked later)
      const size_t gp = rp + ps + idx;
      labn = labels[gp];
      prn = pred4[gp];
      gvn = gt4[gp];
    }

    // compute chunk k from this wave's LDS (staged + drained last iteration)
    const int cnt = min(64, spc - (k << 6));
    prior21(&cbuf[lane * C_], labr, prr, gvr, lane < cnt, sm, cp, cn, np);

    asm volatile("s_waitcnt vmcnt(0)" ::: "memory");  // per-wave drain, no barrier
    __builtin_amdgcn_sched_barrier(0);
    labr = labn; prr = prn; gvr = gvn;
  }

  // ---- block reduction (2 waves, same row) -> private float4 slot ----
  const float r0 = waveSumF(sm), r1 = waveSumF(cp), r2 = waveSumF(cn);
  const int r3 = waveSumI(np);
  if (lane == 0) { redf[wid] = r0; redf[2 + wid] = r1; redf[4 + wid] = r2; redi[wid] = r3; }
  __syncthreads();
  if (tid == 0) {
    part[blockIdx.x] = make_float4(redf[0] + redf[1], redf[2] + redf[3],
                                   redf[4] + redf[5], (float)(redi[0] + redi[1]));
  }
}

// ---------------- fused tail: reduce + decide + (cold) top-k + finalize ----------------
__device__ __forceinline__ unsigned keyCE(const float* __restrict__ conf,
                                          const int* __restrict__ labels,
                                          int b, int p, float& ce) {
  const float* row = conf + ((size_t)b * P_ + p) * C_;
  float m = row[0];
  for (int c = 1; c < C_; ++c) m = fmaxf(m, row[c]);
  float s = 0.f;
  for (int c = 0; c < C_; ++c) s += __expf(row[c] - m);
  const float lse = m + __logf(s);
  const int lab = labels[(size_t)b * P_ + p];
  ce = lse - row[lab];
  if (lab > 0) return 0u;  // positives excluded
  unsigned u = __float_as_uint(lse - row[0]);  // bg_loss -> order-preserving key
  u = (u & 0x80000000u) ? ~u : (u | 0x80000000u);
  return u ? u : 1u;
}

__global__ __launch_bounds__(128) void k_tail(
    const float4* __restrict__ part, const float* __restrict__ conf,
    const int* __restrict__ labels, float* __restrict__ out) {
  const int tid = threadIdx.x;  // 128 threads = 2 waves; thread t owns row t
  const int wid = tid >> 6, lane = tid & 63;
  __shared__ int s_np[B_], s_flag[B_];
  __shared__ double sdA[2], sdB[2], sdC[2];
  __shared__ int siN[2];
  __shared__ double s_extra;
  __shared__ int icnt[2];
  __shared__ float fsum[2];

  // per-row gather over this row's SLOTS partials (deterministic fixed order)
  double sm = 0.0, cp = 0.0, cnSel = 0.0;
  int npr = 0;
  {
    double cn = 0.0;
#pragma unroll
    for (int i = 0; i < SLOTS; ++i) {
      const float4 v = part[tid * SLOTS + i];
      sm += (double)v.x;
      cp += (double)v.y;
      cn += (double)v.z;
      npr += (int)v.w;
    }
    s_np[tid] = npr;
    const int fl = (3 * npr < P_ - npr) ? 1 : 0;  // hot: all negs mined -> 0
    s_flag[tid] = fl;
    if (!fl) cnSel = cn;
  }
  const double t1 = waveSumD(sm), t2 = waveSumD(cp), t3 = waveSumD(cnSel);
  const int t4 = waveSumI(npr);
  if (lane == 0) { sdA[wid] = t1; sdB[wid] = t2; sdC[wid] = t3; siN[wid] = t4; }
  if (tid == 0) s_extra = 0.0;
  __syncthreads();

  // cold path: general top-k fallback (never taken for this data)
  for (int b = 0; b < B_; ++b) {
    if (!s_flag[b]) continue;  // uniform (LDS)
    const int need = 3 * s_np[b];
    unsigned long long lo = 1, hi = 0xFFFFFFFFull, ans = 1;
    while (lo <= hi) {
      const unsigned long long mid = lo + ((hi - lo) >> 1);
      int c = 0;
      float dummy;
      for (int p = tid; p < P_; p += 128)
        if ((unsigned long long)keyCE(conf, labels, b, p, dummy) >= mid) c++;
      c = waveSumI(c);
      if (lane == 0) icnt[wid] = c;
      __syncthreads();
      const int tot = icnt[0] + icnt[1];
      if (tot >= need) { ans = mid; lo = mid + 1; } else { hi = mid - 1; }
      __syncthreads();
    }
    int cgt = 0;
    float sgt = 0.f;
    for (int p = tid; p < P_; p += 128) {
      float ce;
      const unsigned long long k = keyCE(conf, labels, b, p, ce);
      if (k > ans) { cgt++; sgt += ce; }
    }
    cgt = waveSumI(cgt);
    sgt = waveSumF(sgt);
    if (lane == 0) { icnt[wid] = cgt; fsum[wid] = sgt; }
    __syncthreads();
    if (tid == 0) {
      const int gtot = icnt[0] + icnt[1];
      double sx = (double)(fsum[0] + fsum[1]);
      int rm = need - gtot;
      int taken = 0;
      for (int p = 0; p < P_ && taken < rm; ++p) {  // stable tie-break by index
        float ce;
        if (keyCE(conf, labels, b, p, ce) == ans) { sx += ce; taken++; }
      }
      s_extra += sx;
    }
    __syncthreads();
  }

  // finalize
  if (tid == 0) {
    const double G0 = sdA[0] + sdA[1];
    const double G1 = sdB[0] + sdB[1];
    const double G2 = sdC[0] + sdC[1] + s_extra;
    const double N = (double)(siN[0] + siN[1]);
    out[0] = (float)(G0 / N);
    out[1] = (float)((G1 + G2) / N);
  }
}

extern "C" void kernel_launch(void* const* d_in, const int* in_sizes, int n_in,
                              void* d_out, int out_size, void* d_ws, size_t ws_size,
                              hipStream_t stream) {
  const float* conf = (const float*)d_in[0];
  const float* pred = (const float*)d_in[1];
  const int* labels = (const int*)d_in[2];
  const float* gt = (const float*)d_in[3];
  float* out = (float*)d_out;

  // ws: part[GRID] float4, fully overwritten by k_main each call (no memset).
  float4* part = (float4*)d_ws;

  hipLaunchKernelGGL(k_main, dim3(GRID), dim3(TPB), 0, stream,
                     conf, pred, labels, gt, part);
  hipLaunchKernelGGL(k_tail, dim3(1), dim3(128), 0, stream,
                     part, conf, labels, out);
}